// Round 2
// baseline (453.411 us; speedup 1.0000x reference)
//
#include <hip/hip_runtime.h>
#include <hip/hip_bf16.h>

#define T_LEN 256
#define B_DIM 128
#define EMB 1024
#define HID 1024
#define NLAB 50
#define M_ROWS (T_LEN * B_DIM)   // 32768
#define N3H 3072
#define NWG_MAIN 4096            // 256 M-tiles x 16 N-tiles
#define NT (EMB / 32)            // 32 K-steps

typedef __attribute__((ext_vector_type(8))) short short8;
typedef __attribute__((ext_vector_type(4))) float f32x4;

// ---- helpers ----
static __device__ __forceinline__ ushort f2b(float x) {
    unsigned u = __builtin_bit_cast(unsigned, x);
    unsigned lsb = (u >> 16) & 1u;
    u += 0x7fffu + lsb;
    return (ushort)(u >> 16);
}
static __device__ __forceinline__ float b2f(ushort u) {
    unsigned v = ((unsigned)u) << 16;
    return __builtin_bit_cast(float, v);
}
static __device__ __forceinline__ void gload16(const ushort* g, ushort* l) {
    __builtin_amdgcn_global_load_lds(
        (const __attribute__((address_space(1))) unsigned int*)g,
        (__attribute__((address_space(3))) unsigned int*)l,
        16, 0, 0);
}
static __device__ __forceinline__ float fast_sigmoid(float y) {
    return 1.f / (1.f + __expf(-y));
}
static __device__ __forceinline__ float fast_tanh(float y) {
    float e = __expf(2.f * y);           // |y| << 40 here, no overflow
    return (e - 1.f) / (e + 1.f);
}

// ---- kernel 1: x = bf16(emb[sentence])  [32768][1024] ----
__global__ __launch_bounds__(256) void gather_convert(
    const int* __restrict__ sent, const float* __restrict__ emb,
    ushort* __restrict__ xb)
{
    const int r = blockIdx.x;
    const int k4 = threadIdx.x * 4;
    const size_t src = (size_t)sent[r] * EMB + k4;
    float4 v = *(const float4*)(emb + src);
    ushort4 o;
    o.x = f2b(v.x); o.y = f2b(v.y); o.z = f2b(v.z); o.w = f2b(v.w);
    *(ushort4*)(xb + (size_t)r * EMB + k4) = o;
}

// ---- kernel 2: Wt[n][k] = bf16(W[k][n])   [3072][1024] ----
__global__ __launch_bounds__(256) void transposeW(
    const float* __restrict__ W, ushort* __restrict__ Wt)
{
    __shared__ float tile[32][33];
    const int n0 = blockIdx.x * 32, k0 = blockIdx.y * 32;
    const int tx = threadIdx.x, ty = threadIdx.y;   // 32 x 8
#pragma unroll
    for (int j = 0; j < 32; j += 8)
        tile[ty + j][tx] = W[(size_t)(k0 + ty + j) * N3H + n0 + tx];
    __syncthreads();
#pragma unroll
    for (int j = 0; j < 32; j += 8)
        Wt[(size_t)(n0 + ty + j) * EMB + k0 + tx] = f2b(tile[tx][ty + j]);
}

// ---- kernel 3: GEMM with depth-2 pipelined staging + fused bias+activation ----
// Grid: 4096 main blocks (z,f) + 8 o-gate blocks.
// A: bf16 [M][1024]; Bt: bf16 [3072][1024] (W transposed).
__global__ __launch_bounds__(256, 3) void gemm_act(
    const ushort* __restrict__ A, const ushort* __restrict__ Bt,
    const float* __restrict__ bias,
    ushort* __restrict__ zb, ushort* __restrict__ fb, ushort* __restrict__ ob)
{
    __shared__ ushort LA[3][128 * 32];   // 3 x 8KB
    __shared__ ushort LB[3][128 * 32];   // 3 x 8KB

    const int tid = threadIdx.x;
    const int lane = tid & 63;
    const int w = tid >> 6;
    const int wr = w >> 1, wc = w & 1;
    const int l15 = lane & 15, lh = lane >> 4;

    const int wg = blockIdx.x;
    const ushort *Ab, *Bb;
    const float* bptr;
    ushort* dst;
    int rowbase, colbase;
    bool use_tanh;
    if (wg < NWG_MAIN) {
        // XCD-chunked bijective swizzle: each XCD L2 gets a contiguous range;
        // within it, nt varies fastest so one A-panel's 16 N-blocks co-run.
        const int w2 = (wg & 7) * (NWG_MAIN / 8) + (wg >> 3);
        const int mt = w2 >> 4, nt = w2 & 15;
        Ab = A + (size_t)mt * 128 * EMB;
        Bb = Bt + (size_t)nt * 128 * EMB;
        bptr = bias + nt * 128;
        rowbase = mt * 128;
        if (nt < 8) { dst = zb; colbase = nt * 128; use_tanh = true; }
        else        { dst = fb; colbase = (nt - 8) * 128; use_tanh = false; }
    } else {
        // o-gate: only last timestep's 128 rows, cols 2048..3071
        const int nb = wg - NWG_MAIN;
        Ab = A + (size_t)(M_ROWS - 128) * EMB;
        Bb = Bt + (size_t)(16 + nb) * 128 * EMB;
        bptr = bias + 2048 + nb * 128;
        dst = ob; rowbase = 0; colbase = nb * 128; use_tanh = false;
    }

    const int s0 = tid, s1 = tid + 256;
    const ushort* ga0 = Ab + (size_t)(s0 & 127) * EMB + (s0 >> 7) * 8;
    const ushort* ga1 = Ab + (size_t)(s1 & 127) * EMB + (s1 >> 7) * 8;
    const ushort* gb0 = Bb + (size_t)(s0 & 127) * EMB + (s0 >> 7) * 8;
    const ushort* gb1 = Bb + (size_t)(s1 & 127) * EMB + (s1 >> 7) * 8;
    ushort* lA = &LA[0][0];
    ushort* lB = &LB[0][0];

#define STAGE(bi, kk) do {                                   \
        const int ko_ = (kk) * 32;                           \
        ushort* la_ = lA + (bi) * (128 * 32);                \
        ushort* lb_ = lB + (bi) * (128 * 32);                \
        gload16(ga0 + ko_, la_ + s0 * 8);                    \
        gload16(ga1 + ko_, la_ + s1 * 8);                    \
        gload16(gb0 + ko_, lb_ + s0 * 8);                    \
        gload16(gb1 + ko_, lb_ + s1 * 8);                    \
    } while (0)

    f32x4 acc[4][4] = {};

    STAGE(0, 0);
    STAGE(1, 1);
    int bufc = 0;
#pragma unroll
    for (int t = 0; t < NT; ++t) {
        // data-t was staged 2 iters ago; allow data-(t+1)'s 4 loads in flight.
        if (t == NT - 1) asm volatile("s_waitcnt vmcnt(0)" ::: "memory");
        else             asm volatile("s_waitcnt vmcnt(4)" ::: "memory");
        __builtin_amdgcn_s_barrier();
        __builtin_amdgcn_sched_barrier(0);
        if (t + 2 < NT) {
            int b2 = bufc + 2; if (b2 >= 3) b2 -= 3;
            STAGE(b2, t + 2);   // overwrites buffer read at iter t-1: safe post-barrier
        }
        const ushort* bA = lA + bufc * (128 * 32);
        const ushort* bB = lB + bufc * (128 * 32);
        short8 af[4], bfr[4];
#pragma unroll
        for (int i = 0; i < 4; i++) {
            af[i]  = *(const short8*)&bA[(size_t)(lh * 128 + wr * 64 + i * 16 + l15) * 8];
            bfr[i] = *(const short8*)&bB[(size_t)(lh * 128 + wc * 64 + i * 16 + l15) * 8];
        }
#pragma unroll
        for (int mi = 0; mi < 4; mi++)
#pragma unroll
            for (int ni = 0; ni < 4; ni++)
                acc[mi][ni] = __builtin_amdgcn_mfma_f32_16x16x32_bf16(
                    af[mi], bfr[ni], acc[mi][ni], 0, 0, 0);
        bufc = (bufc == 2) ? 0 : bufc + 1;
    }
#undef STAGE

#pragma unroll
    for (int mi = 0; mi < 4; mi++) {
#pragma unroll
        for (int ni = 0; ni < 4; ni++) {
            const int nb = wc * 64 + ni * 16 + l15;
            const float bv = bptr[nb];
            const int rb = rowbase + wr * 64 + mi * 16 + lh * 4;
#pragma unroll
            for (int r = 0; r < 4; r++) {
                float y = acc[mi][ni][r] + bv;
                float a = use_tanh ? fast_tanh(y) : fast_sigmoid(y);
                dst[(size_t)(rb + r) * HID + colbase + nb] = f2b(a);
            }
        }
    }
}

// ---- kernel 4: fo-pool scan over T; h = o_last * c_last ----
__global__ __launch_bounds__(256) void fo_pool(
    const unsigned* __restrict__ z32, const unsigned* __restrict__ fz32,
    const unsigned* __restrict__ o32, float* __restrict__ hbuf)
{
    const int p = blockIdx.x * 256 + threadIdx.x;  // 0..65535 (pairs of h)
    float c0 = 0.f, c1 = 0.f;
#pragma unroll 8
    for (int t = 0; t < T_LEN; ++t) {
        unsigned zz = z32[(size_t)t * (B_DIM * HID / 2) + p];
        unsigned ff = fz32[(size_t)t * (B_DIM * HID / 2) + p];
        float z0 = b2f((ushort)(zz & 0xffffu)), z1 = b2f((ushort)(zz >> 16));
        float f0 = b2f((ushort)(ff & 0xffffu)), f1 = b2f((ushort)(ff >> 16));
        c0 += f0 * (z0 - c0);
        c1 += f1 * (z1 - c1);
    }
    unsigned oo = o32[p];
    float o0 = b2f((ushort)(oo & 0xffffu)), o1 = b2f((ushort)(oo >> 16));
    hbuf[2 * p]     = o0 * c0;
    hbuf[2 * p + 1] = o1 * c1;
}

// ---- kernel 5: logits = h @ Wout + bout; log_softmax ----
__global__ __launch_bounds__(64) void classify(
    const float* __restrict__ hbuf, const float* __restrict__ Wout,
    const float* __restrict__ bout, float* __restrict__ out)
{
    __shared__ float hs[HID];
    const int b = blockIdx.x, l = threadIdx.x;
#pragma unroll
    for (int j = 0; j < HID; j += 64) hs[j + l] = hbuf[(size_t)b * HID + j + l];
    __syncthreads();
    float acc = -1e30f;
    if (l < NLAB) {
        float s = bout[l];
#pragma unroll 4
        for (int e = 0; e < HID; e++) s += hs[e] * Wout[(size_t)e * NLAB + l];
        acc = s;
    }
    float m = acc;
#pragma unroll
    for (int off = 32; off; off >>= 1) m = fmaxf(m, __shfl_xor(m, off));
    float ex = (l < NLAB) ? expf(acc - m) : 0.f;
    float sum = ex;
#pragma unroll
    for (int off = 32; off; off >>= 1) sum += __shfl_xor(sum, off);
    if (l < NLAB) out[(size_t)b * NLAB + l] = acc - m - logf(sum);
}

extern "C" void kernel_launch(void* const* d_in, const int* in_sizes, int n_in,
                              void* d_out, int out_size, void* d_ws, size_t ws_size,
                              hipStream_t stream) {
    const int* sent = (const int*)d_in[0];
    const float* emb = (const float*)d_in[1];
    const float* W = (const float*)d_in[2];
    const float* bias = (const float*)d_in[3];
    const float* Wout = (const float*)d_in[4];
    const float* bout = (const float*)d_in[5];
    float* out = (float*)d_out;

    ushort* xb = (ushort*)d_ws;                      // 32768*1024 bf16
    ushort* Wt = xb + (size_t)M_ROWS * EMB;          // 3072*1024 bf16
    ushort* zb = Wt + (size_t)N3H * EMB;             // 32768*1024 bf16
    ushort* fb = zb + (size_t)M_ROWS * HID;          // 32768*1024 bf16
    ushort* ob = fb + (size_t)M_ROWS * HID;          // 128*1024 bf16
    float* hb = (float*)(ob + (size_t)B_DIM * HID);  // 128*1024 f32

    hipLaunchKernelGGL(gather_convert, dim3(M_ROWS), dim3(256), 0, stream,
                       sent, emb, xb);
    hipLaunchKernelGGL(transposeW, dim3(N3H / 32, EMB / 32), dim3(32, 8), 0, stream,
                       W, Wt);
    // all three gate GEMMs in one launch (z,f full M; o last timestep only)
    hipLaunchKernelGGL(gemm_act, dim3(NWG_MAIN + 8), dim3(256), 0, stream,
                       xb, Wt, bias, zb, fb, ob);
    hipLaunchKernelGGL(fo_pool, dim3(B_DIM * HID / 2 / 256), dim3(256), 0, stream,
                       (const unsigned*)zb, (const unsigned*)fb,
                       (const unsigned*)ob, hb);
    hipLaunchKernelGGL(classify, dim3(B_DIM), dim3(64), 0, stream,
                       hb, Wout, bout, out);
}

// Round 3
// 433.756 us; speedup vs baseline: 1.0453x; 1.0453x over previous
//
#include <hip/hip_runtime.h>
#include <hip/hip_bf16.h>

#define T_LEN 256
#define B_DIM 128
#define EMB 1024
#define HID 1024
#define NLAB 50
#define M_ROWS (T_LEN * B_DIM)   // 32768
#define N3H 3072
#define KTILES 32                // 1024 / BK=32

typedef __attribute__((ext_vector_type(8))) short short8;
typedef __attribute__((ext_vector_type(4))) float f32x4;

// ---- helpers ----
static __device__ __forceinline__ ushort f2b(float x) {
    unsigned u = __builtin_bit_cast(unsigned, x);
    unsigned lsb = (u >> 16) & 1u;
    u += 0x7fffu + lsb;
    return (ushort)(u >> 16);
}
static __device__ __forceinline__ float b2f(ushort u) {
    unsigned v = ((unsigned)u) << 16;
    return __builtin_bit_cast(float, v);
}
static __device__ __forceinline__ void gload16(const ushort* g, ushort* l) {
    __builtin_amdgcn_global_load_lds(
        (const __attribute__((address_space(1))) unsigned int*)g,
        (__attribute__((address_space(3))) unsigned int*)l,
        16, 0, 0);
}
static __device__ __forceinline__ float fast_sigmoid(float y) {
    return 1.f / (1.f + __expf(-y));
}
static __device__ __forceinline__ float fast_tanh(float y) {
    float e = __expf(2.f * y);
    return (e - 1.f) / (e + 1.f);
}

// ---- kernel 1: x = bf16(emb[sentence]), 16 rows per block ----
__global__ __launch_bounds__(256) void gather_convert(
    const int* __restrict__ sent, const float* __restrict__ emb,
    ushort* __restrict__ xb)
{
    const int row = blockIdx.x * 16 + (threadIdx.x >> 4);
    const int seg = threadIdx.x & 15;
    const size_t src = (size_t)sent[row] * EMB;
    const float4* ep = (const float4*)(emb + src);
    ushort4* op = (ushort4*)(xb + (size_t)row * EMB);
#pragma unroll
    for (int j = 0; j < 16; j++) {
        float4 v = ep[seg + j * 16];
        ushort4 o;
        o.x = f2b(v.x); o.y = f2b(v.y); o.z = f2b(v.z); o.w = f2b(v.w);
        op[seg + j * 16] = o;
    }
}

// ---- kernel 2: Wt[n][k] = bf16(W[k][n]) ----
__global__ __launch_bounds__(256) void transposeW(
    const float* __restrict__ W, ushort* __restrict__ Wt)
{
    __shared__ float tile[32][33];
    const int n0 = blockIdx.x * 32, k0 = blockIdx.y * 32;
    const int tx = threadIdx.x, ty = threadIdx.y;   // 32 x 8
#pragma unroll
    for (int j = 0; j < 32; j += 8)
        tile[ty + j][tx] = W[(size_t)(k0 + ty + j) * N3H + n0 + tx];
    __syncthreads();
#pragma unroll
    for (int j = 0; j < 32; j += 8)
        Wt[(size_t)(n0 + ty + j) * EMB + k0 + tx] = f2b(tile[tx][ty + j]);
}

// ---- kernel 3: 256x256 8-wave phase-interleaved GEMM, fused bias+act ----
// A: bf16 [M][1024]; Bt: bf16 [3072][1024].
// Blocks 0..1023: z/f (mt 0..127 x nt 0..7). Blocks 1024..1027: o-gate
// (last 128 rows x cols 2048+q*256), masked stores.
__global__ __launch_bounds__(512, 2) void gemm256(
    const ushort* __restrict__ A, const ushort* __restrict__ Bt,
    const float* __restrict__ bias,
    ushort* __restrict__ zb, ushort* __restrict__ fb, ushort* __restrict__ ob)
{
    __shared__ ushort LDS[65536];   // 4 K-tile buffers x (A 16KB + B 16KB) = 128KB

    const int tid = threadIdx.x;
    const int lane = tid & 63;
    const int w = tid >> 6;
    const int wr = w >> 2, wc = w & 3;          // 2 x 4 wave grid
    const int l15 = lane & 15, lh = lane >> 4;

    const int wg = blockIdx.x;
    const ushort *Ab, *Bb;
    const float* bptr;
    ushort* dst;
    int rowbase, colbase, Mvalid, maxrow;
    bool use_tanh;
    if (wg < 1024) {
        // XCD-chunked bijective swizzle, nt-fastest for A L2 reuse
        const int w2 = (wg & 7) * 128 + (wg >> 3);
        const int mt = w2 >> 3, nt = w2 & 7;
        Ab = A + (size_t)mt * 256 * EMB;
        Bb = Bt + (size_t)nt * 256 * EMB;
        bptr = bias + nt * 256;
        rowbase = mt * 256; Mvalid = 256; maxrow = 255;
        if (nt < 4) { dst = zb; colbase = nt * 256; use_tanh = true; }
        else        { dst = fb; colbase = nt * 256 - 1024; use_tanh = false; }
    } else {
        const int q = wg - 1024;
        Ab = A + (size_t)(M_ROWS - 128) * EMB;
        Bb = Bt + (size_t)(2048 + q * 256) * EMB;
        bptr = bias + 2048 + q * 256;
        rowbase = 0; colbase = q * 256; Mvalid = 128; maxrow = 127;
        dst = ob; use_tanh = false;
    }

    // read-side LDS offsets (ushort units); chunk-XOR swizzle kc^=((r^(r>>2))&3)
    int adA[8], adB[4];
#pragma unroll
    for (int mi = 0; mi < 8; mi++) {
        const int r = wr * 128 + mi * 16 + l15;
        adA[mi] = (r * 4 + (lh ^ ((r ^ (r >> 2)) & 3))) * 8;
    }
#pragma unroll
    for (int ni = 0; ni < 4; ni++) {
        const int r = wc * 64 + ni * 16 + l15;
        adB[ni] = (r * 4 + (lh ^ ((r ^ (r >> 2)) & 3))) * 8;
    }

    // stage-side: thread handles chunks c0=tid, c1=tid+512 of each 1024-chunk tile
    const int c0 = tid, c1 = tid + 512;
    const int r0 = c0 >> 2, s0 = c0 & 3;
    const int r1 = c1 >> 2, s1 = c1 & 3;
    const int p0 = s0 ^ ((r0 ^ (r0 >> 2)) & 3);
    const int p1 = s1 ^ ((r1 ^ (r1 >> 2)) & 3);
    const ushort* gA0 = Ab + (size_t)min(r0, maxrow) * EMB + p0 * 8;
    const ushort* gA1 = Ab + (size_t)min(r1, maxrow) * EMB + p1 * 8;
    const ushort* gB0 = Bb + (size_t)r0 * EMB + p0 * 8;
    const ushort* gB1 = Bb + (size_t)r1 * EMB + p1 * 8;

#define STAGE_A(b2, kt2) do { ushort* lb_ = &LDS[(b2) * 16384];        \
        gload16(gA0 + (kt2) * 32, lb_ + c0 * 8);                        \
        gload16(gA1 + (kt2) * 32, lb_ + c1 * 8); } while (0)
#define STAGE_B(b2, kt2) do { ushort* lb_ = &LDS[(b2) * 16384 + 8192];  \
        gload16(gB0 + (kt2) * 32, lb_ + c0 * 8);                        \
        gload16(gB1 + (kt2) * 32, lb_ + c1 * 8); } while (0)

#define MFMA_Q(AI, ar)                                                               \
    acc[AI][0] = __builtin_amdgcn_mfma_f32_16x16x32_bf16(ar, b0, acc[AI][0], 0,0,0); \
    acc[AI][1] = __builtin_amdgcn_mfma_f32_16x16x32_bf16(ar, b1, acc[AI][1], 0,0,0); \
    acc[AI][2] = __builtin_amdgcn_mfma_f32_16x16x32_bf16(ar, b2, acc[AI][2], 0,0,0); \
    acc[AI][3] = __builtin_amdgcn_mfma_f32_16x16x32_bf16(ar, b3, acc[AI][3], 0,0,0);

    f32x4 acc[8][4] = {};

    // prologue: tiles 0,1 staged; wait tile 0 (leave tile 1's 4 in flight)
    STAGE_A(0, 0); STAGE_B(0, 0);
    STAGE_A(1, 1); STAGE_B(1, 1);
    asm volatile("s_waitcnt vmcnt(4)" ::: "memory");
    __builtin_amdgcn_s_barrier();
    __builtin_amdgcn_sched_barrier(0);

    for (int t = 0; t < KTILES; ++t) {
        const ushort* Ablk = &LDS[(t & 3) * 16384];
        const ushort* Bblk = Ablk + 8192;
        short8 a0, a1, a2, a3, b0, b1, b2, b3;

        // ---- phase 0: mi 0-3 x ni 0-3 ----
        a0 = *(const short8*)&Ablk[adA[0]];
        a1 = *(const short8*)&Ablk[adA[1]];
        a2 = *(const short8*)&Ablk[adA[2]];
        a3 = *(const short8*)&Ablk[adA[3]];
        b0 = *(const short8*)&Bblk[adB[0]];
        b1 = *(const short8*)&Bblk[adB[1]];
        b2 = *(const short8*)&Bblk[adB[2]];
        b3 = *(const short8*)&Bblk[adB[3]];
        if (t < KTILES - 2) STAGE_A((t + 2) & 3, t + 2);
        __builtin_amdgcn_s_barrier();
        asm volatile("s_waitcnt lgkmcnt(0)" ::: "memory");
        __builtin_amdgcn_sched_barrier(0);
        __builtin_amdgcn_s_setprio(1);
        MFMA_Q(0, a0) MFMA_Q(1, a1) MFMA_Q(2, a2) MFMA_Q(3, a3)
        __builtin_amdgcn_s_setprio(0);
        __builtin_amdgcn_s_barrier();
        __builtin_amdgcn_sched_barrier(0);

        // ---- phase 1: mi 4-7 x ni 0-3 (bfr reused) ----
        a0 = *(const short8*)&Ablk[adA[4]];
        a1 = *(const short8*)&Ablk[adA[5]];
        a2 = *(const short8*)&Ablk[adA[6]];
        a3 = *(const short8*)&Ablk[adA[7]];
        if (t < KTILES - 2) STAGE_B((t + 2) & 3, t + 2);
        __builtin_amdgcn_s_barrier();
        asm volatile("s_waitcnt lgkmcnt(0)" ::: "memory");
        __builtin_amdgcn_sched_barrier(0);
        __builtin_amdgcn_s_setprio(1);
        MFMA_Q(4, a0) MFMA_Q(5, a1) MFMA_Q(6, a2) MFMA_Q(7, a3)
        __builtin_amdgcn_s_setprio(0);
        // counted vmcnt once per K-tile: tile t+1 must be resident after this
        // barrier; tile t+2's 4 loads (staged this iter) stay in flight.
        if (t < KTILES - 2)       asm volatile("s_waitcnt vmcnt(4)" ::: "memory");
        else if (t == KTILES - 2) asm volatile("s_waitcnt vmcnt(0)" ::: "memory");
        __builtin_amdgcn_s_barrier();
        __builtin_amdgcn_sched_barrier(0);
    }
#undef STAGE_A
#undef STAGE_B
#undef MFMA_Q

    // epilogue: bias + activation + bf16 store (masked rows for o-blocks)
#pragma unroll
    for (int ni = 0; ni < 4; ni++) {
        const int nb = wc * 64 + ni * 16 + l15;
        const float bv = bptr[nb];
#pragma unroll
        for (int mi = 0; mi < 8; mi++) {
            const int rl = wr * 128 + mi * 16 + lh * 4;
#pragma unroll
            for (int r = 0; r < 4; r++) {
                if (rl + r < Mvalid) {
                    float y = acc[mi][ni][r] + bv;
                    float a = use_tanh ? fast_tanh(y) : fast_sigmoid(y);
                    dst[(size_t)(rowbase + rl + r) * HID + colbase + nb] = f2b(a);
                }
            }
        }
    }
}

// ---- kernel 4: fo-pool scan over T; h = o_last * c_last ----
__global__ __launch_bounds__(256) void fo_pool(
    const unsigned* __restrict__ z32, const unsigned* __restrict__ fz32,
    const unsigned* __restrict__ o32, float* __restrict__ hbuf)
{
    const int p = blockIdx.x * 256 + threadIdx.x;  // pairs of h
    float c0 = 0.f, c1 = 0.f;
#pragma unroll 8
    for (int t = 0; t < T_LEN; ++t) {
        unsigned zz = z32[(size_t)t * (B_DIM * HID / 2) + p];
        unsigned ff = fz32[(size_t)t * (B_DIM * HID / 2) + p];
        float z0 = b2f((ushort)(zz & 0xffffu)), z1 = b2f((ushort)(zz >> 16));
        float f0 = b2f((ushort)(ff & 0xffffu)), f1 = b2f((ushort)(ff >> 16));
        c0 += f0 * (z0 - c0);
        c1 += f1 * (z1 - c1);
    }
    unsigned oo = o32[p];
    float o0 = b2f((ushort)(oo & 0xffffu)), o1 = b2f((ushort)(oo >> 16));
    hbuf[2 * p]     = o0 * c0;
    hbuf[2 * p + 1] = o1 * c1;
}

// ---- kernel 5: logits = h @ Wout + bout; log_softmax ----
__global__ __launch_bounds__(64) void classify(
    const float* __restrict__ hbuf, const float* __restrict__ Wout,
    const float* __restrict__ bout, float* __restrict__ out)
{
    __shared__ float hs[HID];
    const int b = blockIdx.x, l = threadIdx.x;
#pragma unroll
    for (int j = 0; j < HID; j += 64) hs[j + l] = hbuf[(size_t)b * HID + j + l];
    __syncthreads();
    float acc = -1e30f;
    if (l < NLAB) {
        float s = bout[l];
#pragma unroll 4
        for (int e = 0; e < HID; e++) s += hs[e] * Wout[(size_t)e * NLAB + l];
        acc = s;
    }
    float m = acc;
#pragma unroll
    for (int off = 32; off; off >>= 1) m = fmaxf(m, __shfl_xor(m, off));
    float ex = (l < NLAB) ? expf(acc - m) : 0.f;
    float sum = ex;
#pragma unroll
    for (int off = 32; off; off >>= 1) sum += __shfl_xor(sum, off);
    if (l < NLAB) out[(size_t)b * NLAB + l] = acc - m - logf(sum);
}

extern "C" void kernel_launch(void* const* d_in, const int* in_sizes, int n_in,
                              void* d_out, int out_size, void* d_ws, size_t ws_size,
                              hipStream_t stream) {
    const int* sent = (const int*)d_in[0];
    const float* emb = (const float*)d_in[1];
    const float* W = (const float*)d_in[2];
    const float* bias = (const float*)d_in[3];
    const float* Wout = (const float*)d_in[4];
    const float* bout = (const float*)d_in[5];
    float* out = (float*)d_out;

    ushort* xb = (ushort*)d_ws;                      // 32768*1024 bf16
    ushort* Wt = xb + (size_t)M_ROWS * EMB;          // 3072*1024 bf16
    ushort* zb = Wt + (size_t)N3H * EMB;             // 32768*1024 bf16
    ushort* fb = zb + (size_t)M_ROWS * HID;          // 32768*1024 bf16
    ushort* ob = fb + (size_t)M_ROWS * HID;          // 128*1024 bf16
    float* hb = (float*)(ob + (size_t)B_DIM * HID);  // 128*1024 f32

    hipLaunchKernelGGL(gather_convert, dim3(M_ROWS / 16), dim3(256), 0, stream,
                       sent, emb, xb);
    hipLaunchKernelGGL(transposeW, dim3(N3H / 32, EMB / 32), dim3(32, 8), 0, stream,
                       W, Wt);
    hipLaunchKernelGGL(gemm256, dim3(1024 + 4), dim3(512), 0, stream,
                       xb, Wt, bias, zb, fb, ob);
    hipLaunchKernelGGL(fo_pool, dim3(B_DIM * HID / 2 / 256), dim3(256), 0, stream,
                       (const unsigned*)zb, (const unsigned*)fb,
                       (const unsigned*)ob, hb);
    hipLaunchKernelGGL(classify, dim3(B_DIM), dim3(64), 0, stream,
                       hb, Wout, bout, out);
}